// Round 16
// baseline (8339.731 us; speedup 1.0000x reference)
//
#include <hip/hip_runtime.h>
#include <math.h>

#define BB 32
#define SS 48
#define HH 1024
#define EE 256
#define VOC 32000
#define GEN 32
#define G3 3072
#define CH 256
#define NLOG (VOC / 128)

typedef float v4f __attribute__((ext_vector_type(4)));

__device__ __forceinline__ float sigf(float x) { return 1.f / (1.f + expf(-x)); }

__global__ __launch_bounds__(256) void embed_en_k(const int* __restrict__ inputs,
                                                  const float* __restrict__ emb,
                                                  float* __restrict__ x) {
    int i = blockIdx.x * 256 + threadIdx.x;
    int row = i >> 8;
    int e = i & 255;
    x[i] = emb[(size_t)inputs[row] * EE + e];
}

__global__ __launch_bounds__(256) void transpose_k(const float* __restrict__ U,
                                                   float* __restrict__ UT,
                                                   int R, int C) {
    __shared__ float t[32][33];
    int tx = threadIdx.x & 31, ty = threadIdx.x >> 5;
    int bx = blockIdx.x * 32;
    int by = blockIdx.y * 32;
#pragma unroll
    for (int i = 0; i < 4; ++i)
        t[ty + 8 * i][tx] = U[(size_t)(by + ty + 8 * i) * C + bx + tx];
    __syncthreads();
#pragma unroll
    for (int i = 0; i < 4; ++i)
        UT[(size_t)(bx + ty + 8 * i) * R + by + tx] = t[tx][ty + 8 * i];
}

// ---------------- fp32 GEMM 64x64 tile, 4x4 micro ----------------
__global__ __launch_bounds__(256) void gemm64(const float* __restrict__ A,
                                              const float* __restrict__ Bm,
                                              const float* __restrict__ bias,
                                              float* __restrict__ C,
                                              int N, int K) {
    __shared__ float As[32][68];
    __shared__ float Bs[32][68];
    int tid = threadIdx.x;
    int tx = tid & 15, ty = tid >> 4;
    int arow = blockIdx.y * 64, bcol = blockIdx.x * 64;
    int am = tid >> 2;
    int aq = tid & 3;
    int bk = tid >> 4;
    int bn = tid & 15;
    float acc[4][4] = {};
    for (int k0 = 0; k0 < K; k0 += 32) {
        float4 a0 = *(const float4*)(A + (size_t)(arow + am) * K + k0 + aq * 8);
        float4 a1 = *(const float4*)(A + (size_t)(arow + am) * K + k0 + aq * 8 + 4);
        float4 b0 = *(const float4*)(Bm + (size_t)(k0 + bk) * N + bcol + bn * 4);
        float4 b1 = *(const float4*)(Bm + (size_t)(k0 + bk + 16) * N + bcol + bn * 4);
        __syncthreads();
        As[aq * 8 + 0][am] = a0.x; As[aq * 8 + 1][am] = a0.y;
        As[aq * 8 + 2][am] = a0.z; As[aq * 8 + 3][am] = a0.w;
        As[aq * 8 + 4][am] = a1.x; As[aq * 8 + 5][am] = a1.y;
        As[aq * 8 + 6][am] = a1.z; As[aq * 8 + 7][am] = a1.w;
        *(float4*)&Bs[bk][bn * 4] = b0;
        *(float4*)&Bs[bk + 16][bn * 4] = b1;
        __syncthreads();
#pragma unroll
        for (int kk = 0; kk < 32; ++kk) {
            float4 a = *(const float4*)&As[kk][ty * 4];
            float4 b = *(const float4*)&Bs[kk][tx * 4];
            acc[0][0] += a.x * b.x; acc[0][1] += a.x * b.y;
            acc[0][2] += a.x * b.z; acc[0][3] += a.x * b.w;
            acc[1][0] += a.y * b.x; acc[1][1] += a.y * b.y;
            acc[1][2] += a.y * b.z; acc[1][3] += a.y * b.w;
            acc[2][0] += a.z * b.x; acc[2][1] += a.z * b.y;
            acc[2][2] += a.z * b.z; acc[2][3] += a.z * b.w;
            acc[3][0] += a.w * b.x; acc[3][1] += a.w * b.y;
            acc[3][2] += a.w * b.z; acc[3][3] += a.w * b.w;
        }
    }
    float4 bb = *(const float4*)&bias[bcol + tx * 4];
#pragma unroll
    for (int i = 0; i < 4; ++i) {
        size_t row = arow + ty * 4 + i;
        *(float4*)(C + row * N + bcol + tx * 4) =
            make_float4(acc[i][0] + bb.x, acc[i][1] + bb.y,
                        acc[i][2] + bb.z, acc[i][3] + bb.w);
    }
}

// ---------------- per-step encoder GRU (r10-proven, exact) ----------------
__global__ __launch_bounds__(384) void enc_step(
    const float* __restrict__ gi,
    const float* __restrict__ UT,
    const float* __restrict__ b1,
    const float* __restrict__ hin,
    float* __restrict__ hout,
    float* __restrict__ seqout,
    int t) {
    __shared__ float hs[32][260];
    __shared__ float ghs[12][33];
    const int tid = threadIdx.x;
    const int c0 = blockIdx.x * 4;
    const int ks = tid & 31;
    const int outIdx = tid >> 5;
    const int cq = outIdx >> 2;
    const int mo = outIdx & 3;
    const float* Ubase = UT + (size_t)(cq * HH + c0) * HH;
    float acc[4][8];
#pragma unroll
    for (int a = 0; a < 4; ++a)
#pragma unroll
        for (int b = 0; b < 8; ++b) acc[a][b] = 0.f;
    for (int ch = 0; ch < HH / CH; ++ch) {
        for (int i = tid; i < 32 * 64; i += 384) {
            int m = i >> 6, q = i & 63;
            *(float4*)&hs[m][q * 4] =
                *(const float4*)&hin[m * HH + ch * CH + q * 4];
        }
        __syncthreads();
#pragma unroll
        for (int j = 0; j < 2; ++j) {
            int kq = (j * 32 + ks) * 4;
            float4 uv[4];
#pragma unroll
            for (int ci = 0; ci < 4; ++ci)
                uv[ci] = *(const float4*)&Ubase[(size_t)ci * HH + ch * CH + kq];
#pragma unroll
            for (int mi = 0; mi < 8; ++mi) {
                float4 hv = *(const float4*)&hs[mo * 8 + mi][kq];
#pragma unroll
                for (int ci = 0; ci < 4; ++ci)
                    acc[ci][mi] += hv.x * uv[ci].x + hv.y * uv[ci].y +
                                   hv.z * uv[ci].z + hv.w * uv[ci].w;
            }
        }
        __syncthreads();
    }
#pragma unroll
    for (int ci = 0; ci < 4; ++ci)
#pragma unroll
        for (int mi = 0; mi < 8; ++mi) {
            float v = acc[ci][mi];
            v += __shfl_xor(v, 1, 64);
            v += __shfl_xor(v, 2, 64);
            v += __shfl_xor(v, 4, 64);
            v += __shfl_xor(v, 8, 64);
            v += __shfl_xor(v, 16, 64);
            if (ks == 0) ghs[cq * 4 + ci][mo * 8 + mi] = v;
        }
    __syncthreads();
    if (tid < 128) {
        int m = tid & 31, c = tid >> 5;
        int col = c0 + c;
        float ghz = ghs[c][m] + b1[col];
        float ghr = ghs[4 + c][m] + b1[HH + col];
        float ghh = ghs[8 + c][m] + b1[2 * HH + col];
        const float* gir = gi + ((size_t)m * SS + t) * G3;
        float z = sigf(gir[col] + ghz);
        float r = sigf(gir[HH + col] + ghr);
        float nn = tanhf(gir[2 * HH + col] + r * ghh);
        float h = z * hin[m * HH + col] + (1.f - z) * nn;
        hout[m * HH + col] = h;
        seqout[((size_t)m * SS + t) * HH + col] = h;
    }
}

// ---------------- decoder GRU step (zero init state), r10-proven ----------------
__global__ __launch_bounds__(384) void dec_step(
    const float* __restrict__ xt, int K,
    const float* __restrict__ WT,
    const float* __restrict__ b0, const float* __restrict__ b1,
    float* __restrict__ hout) {
    __shared__ float hs[32][260];
    __shared__ float ghs[12][33];
    const int tid = threadIdx.x;
    const int c0 = blockIdx.x * 4;
    const int ks = tid & 31;
    const int outIdx = tid >> 5;
    const int cq = outIdx >> 2;
    const int mo = outIdx & 3;
    const float* Ubase = WT + (size_t)(cq * HH + c0) * K;
    float acc[4][8];
#pragma unroll
    for (int a = 0; a < 4; ++a)
#pragma unroll
        for (int b = 0; b < 8; ++b) acc[a][b] = 0.f;
    const int nch = K / CH;
    for (int ch = 0; ch < nch; ++ch) {
        for (int i = tid; i < 32 * 64; i += 384) {
            int m = i >> 6, q = i & 63;
            *(float4*)&hs[m][q * 4] =
                *(const float4*)&xt[(size_t)m * K + ch * CH + q * 4];
        }
        __syncthreads();
#pragma unroll
        for (int j = 0; j < 2; ++j) {
            int kq = (j * 32 + ks) * 4;
            float4 uv[4];
#pragma unroll
            for (int ci = 0; ci < 4; ++ci)
                uv[ci] = *(const float4*)&Ubase[(size_t)ci * K + ch * CH + kq];
#pragma unroll
            for (int mi = 0; mi < 8; ++mi) {
                float4 hv = *(const float4*)&hs[mo * 8 + mi][kq];
#pragma unroll
                for (int ci = 0; ci < 4; ++ci)
                    acc[ci][mi] += hv.x * uv[ci].x + hv.y * uv[ci].y +
                                   hv.z * uv[ci].z + hv.w * uv[ci].w;
            }
        }
        __syncthreads();
    }
#pragma unroll
    for (int ci = 0; ci < 4; ++ci)
#pragma unroll
        for (int mi = 0; mi < 8; ++mi) {
            float v = acc[ci][mi];
            v += __shfl_xor(v, 1, 64);
            v += __shfl_xor(v, 2, 64);
            v += __shfl_xor(v, 4, 64);
            v += __shfl_xor(v, 8, 64);
            v += __shfl_xor(v, 16, 64);
            if (ks == 0) ghs[cq * 4 + ci][mo * 8 + mi] = v;
        }
    __syncthreads();
    if (tid < 128) {
        int m = tid & 31, c = tid >> 5;
        int col = c0 + c;
        float z = sigf(ghs[c][m] + b0[col] + b1[col]);
        float r = sigf(ghs[4 + c][m] + b0[HH + col] + b1[HH + col]);
        float nn = tanhf(ghs[8 + c][m] + b0[2 * HH + col] + r * b1[2 * HH + col]);
        hout[m * HH + col] = (1.f - z) * nn;
    }
}

// ---------------- fused decoder front (r14-proven, exact) ----------------
__global__ __launch_bounds__(384) void dec_front(
    const float* __restrict__ qb, const float* __restrict__ encP,
    const float* __restrict__ vvec, const float* __restrict__ vb,
    const float* __restrict__ emb_fr, const int* __restrict__ start_id,
    const float* __restrict__ pmv, const int* __restrict__ pmi, int nb,
    const float* __restrict__ P, const float* __restrict__ W0,
    const float* __restrict__ b0, const float* __restrict__ b1,
    float* __restrict__ h1out) {
    __shared__ float sc[SS];
    __shared__ float wsm[SS];
    __shared__ float sv[256];
    __shared__ int si[256];
    __shared__ int stok;
    __shared__ float embl[EE];
    __shared__ float g[3][128];
    const int tid = threadIdx.x;
    const int b = blockIdx.x & 31;
    const int j0 = (blockIdx.x >> 5) * 128;
    const int wave = tid >> 6, lane = tid & 63;
    if (nb == 0) {
        if (tid == 0) stok = start_id[0];
    } else {
        if (tid < 256) {
            float best = -3.4e38f; int bi = 0x7fffffff;
            for (int i = tid; i < nb; i += 256) {
                float v = pmv[(size_t)b * nb + i];
                int ix = pmi[(size_t)b * nb + i];
                if (v > best || (v == best && ix < bi)) { best = v; bi = ix; }
            }
            sv[tid] = best; si[tid] = bi;
        }
        __syncthreads();
        for (int s = 128; s; s >>= 1) {
            if (tid < s) {
                if (sv[tid + s] > sv[tid] ||
                    (sv[tid + s] == sv[tid] && si[tid + s] < si[tid])) {
                    sv[tid] = sv[tid + s]; si[tid] = si[tid + s];
                }
            }
            __syncthreads();
        }
        if (tid == 0) stok = si[0];
    }
    __syncthreads();
    if (tid < EE) embl[tid] = emb_fr[(size_t)stok * EE + tid];
    const float* q = qb + (size_t)b * HH;
    for (int s = wave; s < SS; s += 6) {
        const float* ep = encP + (size_t)(b * SS + s) * HH;
        float sum = 0.f;
        for (int h = lane; h < HH; h += 64)
            sum += tanhf(q[h] + ep[h]) * vvec[h];
#pragma unroll
        for (int o = 32; o; o >>= 1) sum += __shfl_xor(sum, o, 64);
        if (lane == 0) sc[s] = sum + vb[0];
    }
    __syncthreads();
    if (tid < 64) {
        float v = (lane < SS) ? sc[lane] : -3.4e38f;
        float m = v;
#pragma unroll
        for (int o = 32; o; o >>= 1) m = fmaxf(m, __shfl_xor(m, o, 64));
        float e = (lane < SS) ? expf(v - m) : 0.f;
        float ssum = e;
#pragma unroll
        for (int o = 32; o; o >>= 1) ssum += __shfl_xor(ssum, o, 64);
        if (lane < SS) wsm[lane] = e / ssum;
    }
    __syncthreads();
    {
        int gate = tid >> 7;
        int col = tid & 127;
        int gcol = gate * HH + j0 + col;
        float acc = b0[gcol];
        const float* Pb = P + (size_t)b * SS * G3 + gcol;
#pragma unroll 8
        for (int s = 0; s < SS; ++s) acc += wsm[s] * Pb[(size_t)s * G3];
        const float* Wb = W0 + (size_t)HH * G3 + gcol;
#pragma unroll 8
        for (int k = 0; k < EE; ++k) acc += embl[k] * Wb[(size_t)k * G3];
        g[gate][col] = acc;
    }
    __syncthreads();
    if (tid < 128) {
        int jj = j0 + tid;
        float z = sigf(g[0][tid] + b1[jj]);
        float r = sigf(g[1][tid] + b1[HH + jj]);
        float nn = tanhf(g[2][tid] + r * b1[2 * HH + jj]);
        h1out[(size_t)b * HH + jj] = (1.f - z) * nn;
    }
}

// ---------------- merged logits + q GEMM: 512 thr, 4-way k-slice ----------------
// Same r14-proven geometry (BN=128, 250 blocks, NT fc_W) but 8 waves/CU:
// 512 threads stage the B tile (2 NT float4 each -> 2x concurrent HBM reqs/CU).
// k-slices reduced via 48KB LDS scratch. q path: r14 256-thread shape, guarded.
__global__ __launch_bounds__(512) void logits_q(const float* __restrict__ A,
                                                const float* __restrict__ fcW,
                                                const float* __restrict__ fcb,
                                                float* __restrict__ Cl,
                                                const float* __restrict__ qW,
                                                const float* __restrict__ qb,
                                                float* __restrict__ Cq,
                                                float* __restrict__ pmv,
                                                int* __restrict__ pmi,
                                                int qonly) {
    __shared__ float As[32][36];
    __shared__ float Bs[32][132];
    __shared__ float red[3][128][32];
    int tid = threadIdx.x;
    int bid = blockIdx.x;
    bool isq = qonly || (bid >= NLOG);
    if (!isq) {
        int bcol = bid * 128;
        int nc = tid & 15, mg = (tid >> 4) & 7, ksl = tid >> 7;   // ksl 0..3
        int am = tid >> 3, aq = tid & 7;                          // A stage: tid<256
        float4 ra;
        if (tid < 256) ra = *(const float4*)(A + (size_t)am * HH + aq * 4);
        float4 rb[2];
#pragma unroll
        for (int it = 0; it < 2; ++it) {
            int lin = it * 512 + tid;
            int k = lin >> 5, q = lin & 31;
            v4f v = __builtin_nontemporal_load(
                (const v4f*)(fcW + (size_t)k * VOC + bcol + q * 4));
            rb[it] = *(float4*)&v;
        }
        float acc[4][8] = {};
        const int nch = HH / 32;
        for (int ch = 0; ch < nch; ++ch) {
            __syncthreads();
            if (tid < 256) {
                As[aq * 4 + 0][am] = ra.x; As[aq * 4 + 1][am] = ra.y;
                As[aq * 4 + 2][am] = ra.z; As[aq * 4 + 3][am] = ra.w;
            }
#pragma unroll
            for (int it = 0; it < 2; ++it) {
                int lin = it * 512 + tid;
                int k = lin >> 5, q = lin & 31;
                *(float4*)&Bs[k][q * 4] = rb[it];
            }
            __syncthreads();
            if (ch + 1 < nch) {
                int k0 = (ch + 1) * 32;
                if (tid < 256)
                    ra = *(const float4*)(A + (size_t)am * HH + k0 + aq * 4);
#pragma unroll
                for (int it = 0; it < 2; ++it) {
                    int lin = it * 512 + tid;
                    int k = lin >> 5, q = lin & 31;
                    v4f v = __builtin_nontemporal_load(
                        (const v4f*)(fcW + (size_t)(k0 + k) * VOC + bcol + q * 4));
                    rb[it] = *(float4*)&v;
                }
            }
#pragma unroll
            for (int kk = 0; kk < 8; ++kk) {
                int k2 = kk * 4 + ksl;
                float a[4], b[8];
                *(float4*)&a[0] = *(const float4*)&As[k2][mg * 4];
                *(float4*)&b[0] = *(const float4*)&Bs[k2][nc * 8];
                *(float4*)&b[4] = *(const float4*)&Bs[k2][nc * 8 + 4];
#pragma unroll
                for (int r = 0; r < 4; ++r)
#pragma unroll
                    for (int j = 0; j < 8; ++j) acc[r][j] += a[r] * b[j];
            }
        }
        __syncthreads();
        if (ksl) {
            int g = tid & 127;
#pragma unroll
            for (int r = 0; r < 4; ++r)
#pragma unroll
                for (int j = 0; j < 8; ++j) red[ksl - 1][g][r * 8 + j] = acc[r][j];
        }
        __syncthreads();
        if (ksl == 0) {
            int g = tid;
#pragma unroll
            for (int s = 0; s < 3; ++s)
#pragma unroll
                for (int r = 0; r < 4; ++r)
#pragma unroll
                    for (int j = 0; j < 8; ++j) acc[r][j] += red[s][g][r * 8 + j];
            float bb[8];
            *(float4*)&bb[0] = *(const float4*)&fcb[bcol + nc * 8];
            *(float4*)&bb[4] = *(const float4*)&fcb[bcol + nc * 8 + 4];
#pragma unroll
            for (int r = 0; r < 4; ++r) {
#pragma unroll
                for (int j = 0; j < 8; ++j) acc[r][j] += bb[j];
                int row = mg * 4 + r;
                float* cp = Cl + (size_t)row * (GEN * VOC) + bcol + nc * 8;
                v4f o0 = {acc[r][0], acc[r][1], acc[r][2], acc[r][3]};
                v4f o1 = {acc[r][4], acc[r][5], acc[r][6], acc[r][7]};
                __builtin_nontemporal_store(o0, (v4f*)cp);
                __builtin_nontemporal_store(o1, (v4f*)(cp + 4));
                float best = acc[r][0]; int bidx = bcol + nc * 8;
#pragma unroll
                for (int j = 1; j < 8; ++j)
                    if (acc[r][j] > best) { best = acc[r][j]; bidx = bcol + nc * 8 + j; }
#pragma unroll
                for (int o = 1; o < 16; o <<= 1) {
                    float pv = __shfl_xor(best, o, 64);
                    int pi = __shfl_xor(bidx, o, 64);
                    if (pv > best || (pv == best && pi < bidx)) { best = pv; bidx = pi; }
                }
                if (nc == 0) {
                    pmv[row * NLOG + bid] = best;
                    pmi[row * NLOG + bid] = bidx;
                }
            }
        }
        return;
    }
    // ---- q path (r14-proven 256-thread shape; extra waves idle) ----
    if (tid < 256) {
        int bcol = (qonly ? bid : bid - NLOG) * 128;
        int nc = tid & 15, mg = (tid >> 4) & 7, ksl = tid >> 7;
        int am = tid >> 3, aq = tid & 7;
        float4 ra = *(const float4*)(A + (size_t)am * HH + aq * 4);
        float4 rb[4];
#pragma unroll
        for (int it = 0; it < 4; ++it) {
            int lin = it * 256 + tid;
            int k = lin >> 5, q = lin & 31;
            rb[it] = *(const float4*)(qW + (size_t)k * HH + bcol + q * 4);
        }
        float acc[4][8] = {};
        const int nch = HH / 32;
        for (int ch = 0; ch < nch; ++ch) {
            __syncthreads();
            As[aq * 4 + 0][am] = ra.x; As[aq * 4 + 1][am] = ra.y;
            As[aq * 4 + 2][am] = ra.z; As[aq * 4 + 3][am] = ra.w;
#pragma unroll
            for (int it = 0; it < 4; ++it) {
                int lin = it * 256 + tid;
                int k = lin >> 5, q = lin & 31;
                *(float4*)&Bs[k][q * 4] = rb[it];
            }
            __syncthreads();
            if (ch + 1 < nch) {
                int k0 = (ch + 1) * 32;
                ra = *(const float4*)(A + (size_t)am * HH + k0 + aq * 4);
#pragma unroll
                for (int it = 0; it < 4; ++it) {
                    int lin = it * 256 + tid;
                    int k = lin >> 5, q = lin & 31;
                    rb[it] = *(const float4*)(qW + (size_t)(k0 + k) * HH + bcol + q * 4);
                }
            }
#pragma unroll
            for (int kk = 0; kk < 16; ++kk) {
                int k2 = kk * 2 + ksl;
                float a[4], b[8];
                *(float4*)&a[0] = *(const float4*)&As[k2][mg * 4];
                *(float4*)&b[0] = *(const float4*)&Bs[k2][nc * 8];
                *(float4*)&b[4] = *(const float4*)&Bs[k2][nc * 8 + 4];
#pragma unroll
                for (int r = 0; r < 4; ++r)
#pragma unroll
                    for (int j = 0; j < 8; ++j) acc[r][j] += a[r] * b[j];
            }
        }
        __syncthreads();
        float* redq = &Bs[0][0];
        if (ksl == 1) {
            int p = tid & 127;
#pragma unroll
            for (int r = 0; r < 4; ++r)
#pragma unroll
                for (int j = 0; j < 8; ++j) redq[p * 32 + r * 8 + j] = acc[r][j];
        }
        __syncthreads();
        if (ksl == 0) {
            int p = tid;
#pragma unroll
            for (int r = 0; r < 4; ++r)
#pragma unroll
                for (int j = 0; j < 8; ++j) acc[r][j] += redq[p * 32 + r * 8 + j];
            float bb[8];
            *(float4*)&bb[0] = *(const float4*)&qb[bcol + nc * 8];
            *(float4*)&bb[4] = *(const float4*)&qb[bcol + nc * 8 + 4];
#pragma unroll
            for (int r = 0; r < 4; ++r) {
#pragma unroll
                for (int j = 0; j < 8; ++j) acc[r][j] += bb[j];
                int row = mg * 4 + r;
                float* cp = Cq + (size_t)row * HH + bcol + nc * 8;
                *(float4*)cp = make_float4(acc[r][0], acc[r][1], acc[r][2], acc[r][3]);
                *(float4*)(cp + 4) = make_float4(acc[r][4], acc[r][5], acc[r][6], acc[r][7]);
            }
        }
    }
}

__global__ __launch_bounds__(256) void init_dec(float* __restrict__ out,
                                                const int* __restrict__ start_id) {
    int idx = blockIdx.x * 256 + threadIdx.x;
    int sid = start_id[0];
    int b = idx / VOC, v = idx % VOC;
    out[(size_t)b * (GEN * VOC) + v] = (v == sid) ? 1.f : 0.f;
}

extern "C" void kernel_launch(void* const* d_in, const int* in_sizes, int n_in,
                              void* d_out, int out_size, void* d_ws, size_t ws_size,
                              hipStream_t stream) {
    const int*   inputs   = (const int*)d_in[0];
    const int*   start_id = (const int*)d_in[2];
    const float* emb_en   = (const float*)d_in[3];
    const float* emb_fr   = (const float*)d_in[4];
    const float* enc_W0   = (const float*)d_in[5];
    const float* enc_U0   = (const float*)d_in[6];
    const float* enc_b0   = (const float*)d_in[7];
    const float* enc_W1   = (const float*)d_in[8];
    const float* enc_U1   = (const float*)d_in[9];
    const float* enc_b1   = (const float*)d_in[10];
    const float* dec_W0   = (const float*)d_in[11];
    const float* dec_b0   = (const float*)d_in[13];
    const float* dec_W1   = (const float*)d_in[14];
    const float* dec_b1   = (const float*)d_in[16];
    const float* attn_W1  = (const float*)d_in[17];
    const float* attn_b1  = (const float*)d_in[18];
    const float* attn_W2  = (const float*)d_in[19];
    const float* attn_b2  = (const float*)d_in[20];
    const float* attn_V   = (const float*)d_in[21];
    const float* attn_Vb  = (const float*)d_in[22];
    const float* fc_W     = (const float*)d_in[23];
    const float* fc_b     = (const float*)d_in[24];
    float* out = (float*)d_out;
    float* ws  = (float*)d_ws;

    float* giA   = ws;                                // gi; later P = encO @ W0a
    float* x_emb = giA + (size_t)BB * SS * G3;
    float* seq0  = x_emb + (size_t)BB * SS * EE;
    float* encO  = seq0 + (size_t)BB * SS * HH;
    float* encP  = encO + (size_t)BB * SS * HH;
    float* h0A   = encP + (size_t)BB * SS * HH;
    float* h0B   = h0A + BB * HH;
    float* h1A   = h0B + BB * HH;                     // enc final hidden / dec rolling
    float* h1B   = h1A + BB * HH;                     // enc ping-pong; later zero-bias
    float* qbuf  = h1B + BB * HH;
    float* h1buf = qbuf + BB * HH;
    float* pmv   = h1buf + BB * HH;
    int*   pmi   = (int*)(pmv + 32 * NLOG);
    float* U0T   = (float*)(pmi + 32 * NLOG);         // later dec_W1T
    float* U1T   = U0T + (size_t)G3 * HH;
    float* Pmat  = giA;      // P [1536][3072], reuses giA after encoder
    float* W1Td  = U0T;      // dec_W1T [3072][1024], reuses U0T after encoder
    float* zb    = h1B;      // zero bias [3072] for the P GEMM

    // ---- encoder ----
    embed_en_k<<<(BB * SS * EE) / 256, 256, 0, stream>>>(inputs, emb_en, x_emb);
    gemm64<<<dim3(G3 / 64, (BB * SS) / 64), 256, 0, stream>>>(
        x_emb, enc_W0, enc_b0, giA, G3, EE);
    transpose_k<<<dim3(96, 32), 256, 0, stream>>>(enc_U0, U0T, HH, G3);
    transpose_k<<<dim3(96, 32), 256, 0, stream>>>(enc_U1, U1T, HH, G3);
    hipMemsetAsync(h0A, 0, BB * HH * sizeof(float), stream);
    for (int t = 0; t < SS; ++t) {
        const float* hin = (t & 1) ? h0B : h0A;
        float* hout = (t & 1) ? h0A : h0B;
        enc_step<<<256, 384, 0, stream>>>(giA, U0T, enc_b0 + G3, hin, hout, seq0, t);
    }
    gemm64<<<dim3(G3 / 64, (BB * SS) / 64), 256, 0, stream>>>(
        seq0, enc_W1, enc_b1, giA, G3, HH);
    hipMemsetAsync(h1A, 0, BB * HH * sizeof(float), stream);
    for (int t = 0; t < SS; ++t) {
        const float* hin = (t & 1) ? h1B : h1A;
        float* hout = (t & 1) ? h1A : h1B;
        enc_step<<<256, 384, 0, stream>>>(giA, U1T, enc_b1 + G3, hin, hout, encO, t);
    }
    // final hidden in h1A (t=47 odd writes h1A)
    gemm64<<<dim3(HH / 64, (BB * SS) / 64), 256, 0, stream>>>(
        encO, attn_W2, attn_b2, encP, HH, HH);

    // ---- decoder prep: W1 transpose + P = encO @ dec_W0[:1024] (zero bias) ----
    transpose_k<<<dim3(96, 32), 256, 0, stream>>>(dec_W1, W1Td, HH, G3);
    hipMemsetAsync(zb, 0, G3 * sizeof(float), stream);
    gemm64<<<dim3(G3 / 64, (BB * SS) / 64), 256, 0, stream>>>(
        encO, dec_W0, zb, Pmat, G3, HH);

    // ---- decoder ----
    init_dec<<<(BB * VOC) / 256, 256, 0, stream>>>(out, start_id);
    logits_q<<<HH / 128, 512, 0, stream>>>(h1A, fc_W, fc_b, out,
                                           attn_W1, attn_b1, qbuf, pmv, pmi, 1);
    for (int step = 1; step < GEN; ++step) {
        dec_front<<<256, 384, 0, stream>>>(qbuf, encP, attn_V, attn_Vb,
                                           emb_fr, start_id, pmv, pmi,
                                           (step == 1) ? 0 : NLOG,
                                           Pmat, dec_W0, dec_b0, dec_b0 + G3,
                                           h1buf);
        dec_step<<<256, 384, 0, stream>>>(h1buf, HH, W1Td, dec_b1,
                                          dec_b1 + G3, h1A);
        logits_q<<<NLOG + HH / 128, 512, 0, stream>>>(h1A, fc_W, fc_b,
                                                      out + (size_t)step * VOC,
                                                      attn_W1, attn_b1, qbuf,
                                                      pmv, pmi, 0);
    }
}

// Round 17
// 6994.748 us; speedup vs baseline: 1.1923x; 1.1923x over previous
//
#include <hip/hip_runtime.h>
#include <math.h>

#define BB 32
#define SS 48
#define HH 1024
#define EE 256
#define VOC 32000
#define GEN 32
#define G3 3072
#define CH 256
#define NLOG (VOC / 128)

typedef float v4f __attribute__((ext_vector_type(4)));

__device__ __forceinline__ float sigf(float x) { return 1.f / (1.f + expf(-x)); }

__global__ __launch_bounds__(256) void embed_en_k(const int* __restrict__ inputs,
                                                  const float* __restrict__ emb,
                                                  float* __restrict__ x) {
    int i = blockIdx.x * 256 + threadIdx.x;
    int row = i >> 8;
    int e = i & 255;
    x[i] = emb[(size_t)inputs[row] * EE + e];
}

__global__ __launch_bounds__(256) void transpose_k(const float* __restrict__ U,
                                                   float* __restrict__ UT,
                                                   int R, int C) {
    __shared__ float t[32][33];
    int tx = threadIdx.x & 31, ty = threadIdx.x >> 5;
    int bx = blockIdx.x * 32;
    int by = blockIdx.y * 32;
#pragma unroll
    for (int i = 0; i < 4; ++i)
        t[ty + 8 * i][tx] = U[(size_t)(by + ty + 8 * i) * C + bx + tx];
    __syncthreads();
#pragma unroll
    for (int i = 0; i < 4; ++i)
        UT[(size_t)(bx + ty + 8 * i) * R + by + tx] = t[tx][ty + 8 * i];
}

// ---------------- fp32 GEMM 64x64 tile, 4x4 micro ----------------
__global__ __launch_bounds__(256) void gemm64(const float* __restrict__ A,
                                              const float* __restrict__ Bm,
                                              const float* __restrict__ bias,
                                              float* __restrict__ C,
                                              int N, int K) {
    __shared__ float As[32][68];
    __shared__ float Bs[32][68];
    int tid = threadIdx.x;
    int tx = tid & 15, ty = tid >> 4;
    int arow = blockIdx.y * 64, bcol = blockIdx.x * 64;
    int am = tid >> 2;
    int aq = tid & 3;
    int bk = tid >> 4;
    int bn = tid & 15;
    float acc[4][4] = {};
    for (int k0 = 0; k0 < K; k0 += 32) {
        float4 a0 = *(const float4*)(A + (size_t)(arow + am) * K + k0 + aq * 8);
        float4 a1 = *(const float4*)(A + (size_t)(arow + am) * K + k0 + aq * 8 + 4);
        float4 b0 = *(const float4*)(Bm + (size_t)(k0 + bk) * N + bcol + bn * 4);
        float4 b1 = *(const float4*)(Bm + (size_t)(k0 + bk + 16) * N + bcol + bn * 4);
        __syncthreads();
        As[aq * 8 + 0][am] = a0.x; As[aq * 8 + 1][am] = a0.y;
        As[aq * 8 + 2][am] = a0.z; As[aq * 8 + 3][am] = a0.w;
        As[aq * 8 + 4][am] = a1.x; As[aq * 8 + 5][am] = a1.y;
        As[aq * 8 + 6][am] = a1.z; As[aq * 8 + 7][am] = a1.w;
        *(float4*)&Bs[bk][bn * 4] = b0;
        *(float4*)&Bs[bk + 16][bn * 4] = b1;
        __syncthreads();
#pragma unroll
        for (int kk = 0; kk < 32; ++kk) {
            float4 a = *(const float4*)&As[kk][ty * 4];
            float4 b = *(const float4*)&Bs[kk][tx * 4];
            acc[0][0] += a.x * b.x; acc[0][1] += a.x * b.y;
            acc[0][2] += a.x * b.z; acc[0][3] += a.x * b.w;
            acc[1][0] += a.y * b.x; acc[1][1] += a.y * b.y;
            acc[1][2] += a.y * b.z; acc[1][3] += a.y * b.w;
            acc[2][0] += a.z * b.x; acc[2][1] += a.z * b.y;
            acc[2][2] += a.z * b.z; acc[2][3] += a.z * b.w;
            acc[3][0] += a.w * b.x; acc[3][1] += a.w * b.y;
            acc[3][2] += a.w * b.z; acc[3][3] += a.w * b.w;
        }
    }
    float4 bb = *(const float4*)&bias[bcol + tx * 4];
#pragma unroll
    for (int i = 0; i < 4; ++i) {
        size_t row = arow + ty * 4 + i;
        *(float4*)(C + row * N + bcol + tx * 4) =
            make_float4(acc[i][0] + bb.x, acc[i][1] + bb.y,
                        acc[i][2] + bb.z, acc[i][3] + bb.w);
    }
}

// ---------------- per-step encoder GRU (r10-proven, exact) ----------------
__global__ __launch_bounds__(384) void enc_step(
    const float* __restrict__ gi,
    const float* __restrict__ UT,
    const float* __restrict__ b1,
    const float* __restrict__ hin,
    float* __restrict__ hout,
    float* __restrict__ seqout,
    int t) {
    __shared__ float hs[32][260];
    __shared__ float ghs[12][33];
    const int tid = threadIdx.x;
    const int c0 = blockIdx.x * 4;
    const int ks = tid & 31;
    const int outIdx = tid >> 5;
    const int cq = outIdx >> 2;
    const int mo = outIdx & 3;
    const float* Ubase = UT + (size_t)(cq * HH + c0) * HH;
    float acc[4][8];
#pragma unroll
    for (int a = 0; a < 4; ++a)
#pragma unroll
        for (int b = 0; b < 8; ++b) acc[a][b] = 0.f;
    for (int ch = 0; ch < HH / CH; ++ch) {
        for (int i = tid; i < 32 * 64; i += 384) {
            int m = i >> 6, q = i & 63;
            *(float4*)&hs[m][q * 4] =
                *(const float4*)&hin[m * HH + ch * CH + q * 4];
        }
        __syncthreads();
#pragma unroll
        for (int j = 0; j < 2; ++j) {
            int kq = (j * 32 + ks) * 4;
            float4 uv[4];
#pragma unroll
            for (int ci = 0; ci < 4; ++ci)
                uv[ci] = *(const float4*)&Ubase[(size_t)ci * HH + ch * CH + kq];
#pragma unroll
            for (int mi = 0; mi < 8; ++mi) {
                float4 hv = *(const float4*)&hs[mo * 8 + mi][kq];
#pragma unroll
                for (int ci = 0; ci < 4; ++ci)
                    acc[ci][mi] += hv.x * uv[ci].x + hv.y * uv[ci].y +
                                   hv.z * uv[ci].z + hv.w * uv[ci].w;
            }
        }
        __syncthreads();
    }
#pragma unroll
    for (int ci = 0; ci < 4; ++ci)
#pragma unroll
        for (int mi = 0; mi < 8; ++mi) {
            float v = acc[ci][mi];
            v += __shfl_xor(v, 1, 64);
            v += __shfl_xor(v, 2, 64);
            v += __shfl_xor(v, 4, 64);
            v += __shfl_xor(v, 8, 64);
            v += __shfl_xor(v, 16, 64);
            if (ks == 0) ghs[cq * 4 + ci][mo * 8 + mi] = v;
        }
    __syncthreads();
    if (tid < 128) {
        int m = tid & 31, c = tid >> 5;
        int col = c0 + c;
        float ghz = ghs[c][m] + b1[col];
        float ghr = ghs[4 + c][m] + b1[HH + col];
        float ghh = ghs[8 + c][m] + b1[2 * HH + col];
        const float* gir = gi + ((size_t)m * SS + t) * G3;
        float z = sigf(gir[col] + ghz);
        float r = sigf(gir[HH + col] + ghr);
        float nn = tanhf(gir[2 * HH + col] + r * ghh);
        float h = z * hin[m * HH + col] + (1.f - z) * nn;
        hout[m * HH + col] = h;
        seqout[((size_t)m * SS + t) * HH + col] = h;
    }
}

// ---------------- decoder GRU step (zero init state), r10-proven ----------------
__global__ __launch_bounds__(384) void dec_step(
    const float* __restrict__ xt, int K,
    const float* __restrict__ WT,
    const float* __restrict__ b0, const float* __restrict__ b1,
    float* __restrict__ hout) {
    __shared__ float hs[32][260];
    __shared__ float ghs[12][33];
    const int tid = threadIdx.x;
    const int c0 = blockIdx.x * 4;
    const int ks = tid & 31;
    const int outIdx = tid >> 5;
    const int cq = outIdx >> 2;
    const int mo = outIdx & 3;
    const float* Ubase = WT + (size_t)(cq * HH + c0) * K;
    float acc[4][8];
#pragma unroll
    for (int a = 0; a < 4; ++a)
#pragma unroll
        for (int b = 0; b < 8; ++b) acc[a][b] = 0.f;
    const int nch = K / CH;
    for (int ch = 0; ch < nch; ++ch) {
        for (int i = tid; i < 32 * 64; i += 384) {
            int m = i >> 6, q = i & 63;
            *(float4*)&hs[m][q * 4] =
                *(const float4*)&xt[(size_t)m * K + ch * CH + q * 4];
        }
        __syncthreads();
#pragma unroll
        for (int j = 0; j < 2; ++j) {
            int kq = (j * 32 + ks) * 4;
            float4 uv[4];
#pragma unroll
            for (int ci = 0; ci < 4; ++ci)
                uv[ci] = *(const float4*)&Ubase[(size_t)ci * K + ch * CH + kq];
#pragma unroll
            for (int mi = 0; mi < 8; ++mi) {
                float4 hv = *(const float4*)&hs[mo * 8 + mi][kq];
#pragma unroll
                for (int ci = 0; ci < 4; ++ci)
                    acc[ci][mi] += hv.x * uv[ci].x + hv.y * uv[ci].y +
                                   hv.z * uv[ci].z + hv.w * uv[ci].w;
            }
        }
        __syncthreads();
    }
#pragma unroll
    for (int ci = 0; ci < 4; ++ci)
#pragma unroll
        for (int mi = 0; mi < 8; ++mi) {
            float v = acc[ci][mi];
            v += __shfl_xor(v, 1, 64);
            v += __shfl_xor(v, 2, 64);
            v += __shfl_xor(v, 4, 64);
            v += __shfl_xor(v, 8, 64);
            v += __shfl_xor(v, 16, 64);
            if (ks == 0) ghs[cq * 4 + ci][mo * 8 + mi] = v;
        }
    __syncthreads();
    if (tid < 128) {
        int m = tid & 31, c = tid >> 5;
        int col = c0 + c;
        float z = sigf(ghs[c][m] + b0[col] + b1[col]);
        float r = sigf(ghs[4 + c][m] + b0[HH + col] + b1[HH + col]);
        float nn = tanhf(ghs[8 + c][m] + b0[2 * HH + col] + r * b1[2 * HH + col]);
        hout[m * HH + col] = (1.f - z) * nn;
    }
}

// ---------------- fused decoder front (r14-proven, exact) ----------------
__global__ __launch_bounds__(384) void dec_front(
    const float* __restrict__ qb, const float* __restrict__ encP,
    const float* __restrict__ vvec, const float* __restrict__ vb,
    const float* __restrict__ emb_fr, const int* __restrict__ start_id,
    const float* __restrict__ pmv, const int* __restrict__ pmi, int nb,
    const float* __restrict__ P, const float* __restrict__ W0,
    const float* __restrict__ b0, const float* __restrict__ b1,
    float* __restrict__ h1out) {
    __shared__ float sc[SS];
    __shared__ float wsm[SS];
    __shared__ float sv[256];
    __shared__ int si[256];
    __shared__ int stok;
    __shared__ float embl[EE];
    __shared__ float g[3][128];
    const int tid = threadIdx.x;
    const int b = blockIdx.x & 31;
    const int j0 = (blockIdx.x >> 5) * 128;
    const int wave = tid >> 6, lane = tid & 63;
    if (nb == 0) {
        if (tid == 0) stok = start_id[0];
    } else {
        if (tid < 256) {
            float best = -3.4e38f; int bi = 0x7fffffff;
            for (int i = tid; i < nb; i += 256) {
                float v = pmv[(size_t)b * nb + i];
                int ix = pmi[(size_t)b * nb + i];
                if (v > best || (v == best && ix < bi)) { best = v; bi = ix; }
            }
            sv[tid] = best; si[tid] = bi;
        }
        __syncthreads();
        for (int s = 128; s; s >>= 1) {
            if (tid < s) {
                if (sv[tid + s] > sv[tid] ||
                    (sv[tid + s] == sv[tid] && si[tid + s] < si[tid])) {
                    sv[tid] = sv[tid + s]; si[tid] = si[tid + s];
                }
            }
            __syncthreads();
        }
        if (tid == 0) stok = si[0];
    }
    __syncthreads();
    if (tid < EE) embl[tid] = emb_fr[(size_t)stok * EE + tid];
    const float* q = qb + (size_t)b * HH;
    for (int s = wave; s < SS; s += 6) {
        const float* ep = encP + (size_t)(b * SS + s) * HH;
        float sum = 0.f;
        for (int h = lane; h < HH; h += 64)
            sum += tanhf(q[h] + ep[h]) * vvec[h];
#pragma unroll
        for (int o = 32; o; o >>= 1) sum += __shfl_xor(sum, o, 64);
        if (lane == 0) sc[s] = sum + vb[0];
    }
    __syncthreads();
    if (tid < 64) {
        float v = (lane < SS) ? sc[lane] : -3.4e38f;
        float m = v;
#pragma unroll
        for (int o = 32; o; o >>= 1) m = fmaxf(m, __shfl_xor(m, o, 64));
        float e = (lane < SS) ? expf(v - m) : 0.f;
        float ssum = e;
#pragma unroll
        for (int o = 32; o; o >>= 1) ssum += __shfl_xor(ssum, o, 64);
        if (lane < SS) wsm[lane] = e / ssum;
    }
    __syncthreads();
    {
        int gate = tid >> 7;
        int col = tid & 127;
        int gcol = gate * HH + j0 + col;
        float acc = b0[gcol];
        const float* Pb = P + (size_t)b * SS * G3 + gcol;
#pragma unroll 8
        for (int s = 0; s < SS; ++s) acc += wsm[s] * Pb[(size_t)s * G3];
        const float* Wb = W0 + (size_t)HH * G3 + gcol;
#pragma unroll 8
        for (int k = 0; k < EE; ++k) acc += embl[k] * Wb[(size_t)k * G3];
        g[gate][col] = acc;
    }
    __syncthreads();
    if (tid < 128) {
        int jj = j0 + tid;
        float z = sigf(g[0][tid] + b1[jj]);
        float r = sigf(g[1][tid] + b1[HH + jj]);
        float nn = tanhf(g[2][tid] + r * b1[2 * HH + jj]);
        h1out[(size_t)b * HH + jj] = (1.f - z) * nn;
    }
}

// ---------------- merged logits + q GEMM (r14-proven, exact) ----------------
__global__ __launch_bounds__(256) void logits_q(const float* __restrict__ A,
                                                const float* __restrict__ fcW,
                                                const float* __restrict__ fcb,
                                                float* __restrict__ Cl,
                                                const float* __restrict__ qW,
                                                const float* __restrict__ qb,
                                                float* __restrict__ Cq,
                                                float* __restrict__ pmv,
                                                int* __restrict__ pmi,
                                                int qonly) {
    __shared__ float As[32][36];
    __shared__ float Bs[32][132];
    int tid = threadIdx.x;
    int bid = blockIdx.x;
    bool isq = qonly || (bid >= NLOG);
    const float* Bm = isq ? qW : fcW;
    const float* bias = isq ? qb : fcb;
    float* C = isq ? Cq : Cl;
    int N = isq ? HH : VOC;
    int ldc = isq ? HH : GEN * VOC;
    int bcol = (isq ? (qonly ? bid : bid - NLOG) : bid) * 128;
    int nc = tid & 15, mg = (tid >> 4) & 7, ksl = tid >> 7;
    const int nch = HH / 32;
    int am = tid >> 3, aq = tid & 7;
    float4 ra = *(const float4*)(A + (size_t)am * HH + aq * 4);
    float4 rb[4];
#pragma unroll
    for (int it = 0; it < 4; ++it) {
        int lin = it * 256 + tid;
        int k = lin >> 5, q = lin & 31;
        const float* p = Bm + (size_t)k * N + bcol + q * 4;
        if (isq) { rb[it] = *(const float4*)p; }
        else { v4f v = __builtin_nontemporal_load((const v4f*)p); rb[it] = *(float4*)&v; }
    }
    float acc[4][8] = {};
    for (int ch = 0; ch < nch; ++ch) {
        __syncthreads();
        As[aq * 4 + 0][am] = ra.x; As[aq * 4 + 1][am] = ra.y;
        As[aq * 4 + 2][am] = ra.z; As[aq * 4 + 3][am] = ra.w;
#pragma unroll
        for (int it = 0; it < 4; ++it) {
            int lin = it * 256 + tid;
            int k = lin >> 5, q = lin & 31;
            *(float4*)&Bs[k][q * 4] = rb[it];
        }
        __syncthreads();
        if (ch + 1 < nch) {
            int k0 = (ch + 1) * 32;
            ra = *(const float4*)(A + (size_t)am * HH + k0 + aq * 4);
#pragma unroll
            for (int it = 0; it < 4; ++it) {
                int lin = it * 256 + tid;
                int k = lin >> 5, q = lin & 31;
                const float* p = Bm + (size_t)(k0 + k) * N + bcol + q * 4;
                if (isq) { rb[it] = *(const float4*)p; }
                else { v4f v = __builtin_nontemporal_load((const v4f*)p); rb[it] = *(float4*)&v; }
            }
        }
#pragma unroll
        for (int kk = 0; kk < 16; ++kk) {
            int k2 = kk * 2 + ksl;
            float a[4], b[8];
            *(float4*)&a[0] = *(const float4*)&As[k2][mg * 4];
            *(float4*)&b[0] = *(const float4*)&Bs[k2][nc * 8];
            *(float4*)&b[4] = *(const float4*)&Bs[k2][nc * 8 + 4];
#pragma unroll
            for (int r = 0; r < 4; ++r)
#pragma unroll
                for (int j = 0; j < 8; ++j) acc[r][j] += a[r] * b[j];
        }
    }
    __syncthreads();
    float* red = &Bs[0][0];
    if (ksl == 1) {
        int p = tid & 127;
#pragma unroll
        for (int r = 0; r < 4; ++r)
#pragma unroll
            for (int j = 0; j < 8; ++j) red[p * 32 + r * 8 + j] = acc[r][j];
    }
    __syncthreads();
    if (ksl == 0) {
        int p = tid;
#pragma unroll
        for (int r = 0; r < 4; ++r)
#pragma unroll
            for (int j = 0; j < 8; ++j) acc[r][j] += red[p * 32 + r * 8 + j];
        float bb[8];
        *(float4*)&bb[0] = *(const float4*)&bias[bcol + nc * 8];
        *(float4*)&bb[4] = *(const float4*)&bias[bcol + nc * 8 + 4];
#pragma unroll
        for (int r = 0; r < 4; ++r) {
#pragma unroll
            for (int j = 0; j < 8; ++j) acc[r][j] += bb[j];
            int row = mg * 4 + r;
            float* cp = C + (size_t)row * ldc + bcol + nc * 8;
            if (isq) {
                *(float4*)cp = make_float4(acc[r][0], acc[r][1], acc[r][2], acc[r][3]);
                *(float4*)(cp + 4) = make_float4(acc[r][4], acc[r][5], acc[r][6], acc[r][7]);
            } else {
                v4f o0 = {acc[r][0], acc[r][1], acc[r][2], acc[r][3]};
                v4f o1 = {acc[r][4], acc[r][5], acc[r][6], acc[r][7]};
                __builtin_nontemporal_store(o0, (v4f*)cp);
                __builtin_nontemporal_store(o1, (v4f*)(cp + 4));
            }
        }
        if (!isq) {
#pragma unroll
            for (int r = 0; r < 4; ++r) {
                float best = acc[r][0]; int bidx = bcol + nc * 8;
#pragma unroll
                for (int j = 1; j < 8; ++j)
                    if (acc[r][j] > best) { best = acc[r][j]; bidx = bcol + nc * 8 + j; }
#pragma unroll
                for (int o = 1; o < 16; o <<= 1) {
                    float pv = __shfl_xor(best, o, 64);
                    int pi = __shfl_xor(bidx, o, 64);
                    if (pv > best || (pv == best && pi < bidx)) { best = pv; bidx = pi; }
                }
                if (nc == 0) {
                    int row = mg * 4 + r;
                    pmv[row * NLOG + bid] = best;
                    pmi[row * NLOG + bid] = bidx;
                }
            }
        }
    }
}

__global__ __launch_bounds__(256) void init_dec(float* __restrict__ out,
                                                const int* __restrict__ start_id) {
    int idx = blockIdx.x * 256 + threadIdx.x;
    int sid = start_id[0];
    int b = idx / VOC, v = idx % VOC;
    out[(size_t)b * (GEN * VOC) + v] = (v == sid) ? 1.f : 0.f;
}

extern "C" void kernel_launch(void* const* d_in, const int* in_sizes, int n_in,
                              void* d_out, int out_size, void* d_ws, size_t ws_size,
                              hipStream_t stream) {
    const int*   inputs   = (const int*)d_in[0];
    const int*   start_id = (const int*)d_in[2];
    const float* emb_en   = (const float*)d_in[3];
    const float* emb_fr   = (const float*)d_in[4];
    const float* enc_W0   = (const float*)d_in[5];
    const float* enc_U0   = (const float*)d_in[6];
    const float* enc_b0   = (const float*)d_in[7];
    const float* enc_W1   = (const float*)d_in[8];
    const float* enc_U1   = (const float*)d_in[9];
    const float* enc_b1   = (const float*)d_in[10];
    const float* dec_W0   = (const float*)d_in[11];
    const float* dec_b0   = (const float*)d_in[13];
    const float* dec_W1   = (const float*)d_in[14];
    const float* dec_b1   = (const float*)d_in[16];
    const float* attn_W1  = (const float*)d_in[17];
    const float* attn_b1  = (const float*)d_in[18];
    const float* attn_W2  = (const float*)d_in[19];
    const float* attn_b2  = (const float*)d_in[20];
    const float* attn_V   = (const float*)d_in[21];
    const float* attn_Vb  = (const float*)d_in[22];
    const float* fc_W     = (const float*)d_in[23];
    const float* fc_b     = (const float*)d_in[24];
    float* out = (float*)d_out;
    float* ws  = (float*)d_ws;

    float* giA   = ws;                                // gi; later P = encO @ W0a
    float* x_emb = giA + (size_t)BB * SS * G3;
    float* seq0  = x_emb + (size_t)BB * SS * EE;
    float* encO  = seq0 + (size_t)BB * SS * HH;
    float* encP  = encO + (size_t)BB * SS * HH;
    float* h0A   = encP + (size_t)BB * SS * HH;
    float* h0B   = h0A + BB * HH;
    float* h1A   = h0B + BB * HH;                     // enc final hidden / dec rolling
    float* h1B   = h1A + BB * HH;                     // enc ping-pong; later zero-bias
    float* qbuf  = h1B + BB * HH;
    float* h1buf = qbuf + BB * HH;
    float* pmv   = h1buf + BB * HH;
    int*   pmi   = (int*)(pmv + 32 * NLOG);
    float* U0T   = (float*)(pmi + 32 * NLOG);         // later dec_W1T
    float* U1T   = U0T + (size_t)G3 * HH;
    float* Pmat  = giA;      // P [1536][3072], reuses giA after encoder
    float* W1Td  = U0T;      // dec_W1T [3072][1024], reuses U0T after encoder
    float* zb    = h1B;      // zero bias [3072] for the P GEMM

    // ---- encoder ----
    embed_en_k<<<(BB * SS * EE) / 256, 256, 0, stream>>>(inputs, emb_en, x_emb);
    gemm64<<<dim3(G3 / 64, (BB * SS) / 64), 256, 0, stream>>>(
        x_emb, enc_W0, enc_b0, giA, G3, EE);
    transpose_k<<<dim3(96, 32), 256, 0, stream>>>(enc_U0, U0T, HH, G3);
    transpose_k<<<dim3(96, 32), 256, 0, stream>>>(enc_U1, U1T, HH, G3);
    hipMemsetAsync(h0A, 0, BB * HH * sizeof(float), stream);
    for (int t = 0; t < SS; ++t) {
        const float* hin = (t & 1) ? h0B : h0A;
        float* hout = (t & 1) ? h0A : h0B;
        enc_step<<<256, 384, 0, stream>>>(giA, U0T, enc_b0 + G3, hin, hout, seq0, t);
    }
    gemm64<<<dim3(G3 / 64, (BB * SS) / 64), 256, 0, stream>>>(
        seq0, enc_W1, enc_b1, giA, G3, HH);
    hipMemsetAsync(h1A, 0, BB * HH * sizeof(float), stream);
    for (int t = 0; t < SS; ++t) {
        const float* hin = (t & 1) ? h1B : h1A;
        float* hout = (t & 1) ? h1A : h1B;
        enc_step<<<256, 384, 0, stream>>>(giA, U1T, enc_b1 + G3, hin, hout, encO, t);
    }
    // final hidden in h1A (t=47 odd writes h1A)
    gemm64<<<dim3(HH / 64, (BB * SS) / 64), 256, 0, stream>>>(
        encO, attn_W2, attn_b2, encP, HH, HH);

    // ---- decoder prep: W1 transpose + P = encO @ dec_W0[:1024] (zero bias) ----
    transpose_k<<<dim3(96, 32), 256, 0, stream>>>(dec_W1, W1Td, HH, G3);
    hipMemsetAsync(zb, 0, G3 * sizeof(float), stream);
    gemm64<<<dim3(G3 / 64, (BB * SS) / 64), 256, 0, stream>>>(
        encO, dec_W0, zb, Pmat, G3, HH);

    // ---- decoder ----
    init_dec<<<(BB * VOC) / 256, 256, 0, stream>>>(out, start_id);
    logits_q<<<HH / 128, 256, 0, stream>>>(h1A, fc_W, fc_b, out,
                                           attn_W1, attn_b1, qbuf, pmv, pmi, 1);
    for (int step = 1; step < GEN; ++step) {
        dec_front<<<256, 384, 0, stream>>>(qbuf, encP, attn_V, attn_Vb,
                                           emb_fr, start_id, pmv, pmi,
                                           (step == 1) ? 0 : NLOG,
                                           Pmat, dec_W0, dec_b0, dec_b0 + G3,
                                           h1buf);
        dec_step<<<256, 384, 0, stream>>>(h1buf, HH, W1Td, dec_b1,
                                          dec_b1 + G3, h1A);
        logits_q<<<NLOG + HH / 128, 256, 0, stream>>>(h1A, fc_W, fc_b,
                                                      out + (size_t)step * VOC,
                                                      attn_W1, attn_b1, qbuf,
                                                      pmv, pmi, 0);
    }
}